// Round 6
// baseline (1739.578 us; speedup 1.0000x reference)
//
#include <hip/hip_runtime.h>

// EdgeAggregate: out[E,64] = segment_sum(feat[nbr[:,1]], nbr[:,0]) @ K[64,64] + bias
//
// R2: bucketed counting-sort build (line-coalesced writes) -- 988 -> 584 us.
// R3: float4 gather (4 rows / wave-instr) + nt stores -- 584 -> 534 us (k_agg 280).
// R4: readlane transform -- REGRESSED (k_agg 309). reverted.
// R5: 3-stage row pipeline -- NEUTRAL (k_agg 288). offs/csr chain was not the limit.
// R6 theory: k_agg variants bracket 280-310 us at ~3.5 TB/s effective gather;
//     limiter = random-gather service + per-row issue overhead. Restructure:
//     delete the per-dst sort (k_bucket/csr/offs) entirely. One block per
//     512-dst half-bucket holds a 128 KB LDS fp32 accumulator; pairs stream
//     straight from k_partition's bucket-major 'part': per pair, 64 lanes do
//     one coalesced 256B feat load + one ds_add_f32 (2-way alias, free).
//     8-deep unroll -> 2 KB in flight/wave, ~6 VALU/pair. Epilogue: uniform
//     ds_read_b128 transform (R3's proven-cheap form) + nt store.

#define FD 64
#define BKT_SHIFT 10
#define BKT_MAX 512            // requires NBKT <= 512  (E <= 524288)
#define TILE_A 8192            // pairs per partition block
#define NDH 512                // dsts per half-bucket block

// ---------------- build pipeline (unchanged from R2) ----------------

__global__ __launch_bounds__(256) void k_bhist(const int2* __restrict__ nbr,
                                               int* __restrict__ bcnt, int P) {
    __shared__ int h[BKT_MAX];
    const int t = threadIdx.x;
    for (int i = t; i < BKT_MAX; i += 256) h[i] = 0;
    __syncthreads();
    const int base = blockIdx.x * 4096;
#pragma unroll
    for (int j = 0; j < 16; ++j) {
        int p = base + j * 256 + t;
        if (p < P) atomicAdd(&h[nbr[p].x >> BKT_SHIFT], 1);
    }
    __syncthreads();
    for (int i = t; i < BKT_MAX; i += 256) {
        int v = h[i];
        if (v) atomicAdd(&bcnt[i], v);
    }
}

__global__ __launch_bounds__(512) void k_bscan(const int* __restrict__ bcnt,
                                               int* __restrict__ bbase,
                                               int* __restrict__ bcur,
                                               int NBKT, int P) {
    __shared__ int s[BKT_MAX];
    const int t = threadIdx.x;
    s[t] = (t < NBKT) ? bcnt[t] : 0;
    __syncthreads();
    int orig = s[t];
    for (int off = 1; off < BKT_MAX; off <<= 1) {
        int v = (t >= off) ? s[t - off] : 0;
        __syncthreads();
        s[t] += v;
        __syncthreads();
    }
    int ex = s[t] - orig;
    if (t < NBKT) {
        bbase[t] = ex;
        bcur[t] = ex;
    }
    if (t == NBKT - 1) bbase[NBKT] = s[t];  // == P
    (void)P;
}

__global__ __launch_bounds__(256) void k_partition(const int2* __restrict__ nbr,
                                                   int* __restrict__ bcur,
                                                   int* __restrict__ part, int P) {
    __shared__ int hist[BKT_MAX];
    __shared__ int off[BKT_MAX];
    __shared__ int curs[BKT_MAX];
    __shared__ int rb[BKT_MAX];
    __shared__ int tsum[256];
    __shared__ int stage_v[TILE_A];
    __shared__ unsigned short stage_b[TILE_A];

    const int t = threadIdx.x;
    const int base = blockIdx.x * TILE_A;

    for (int i = t; i < BKT_MAX; i += 256) hist[i] = 0;
    __syncthreads();

#pragma unroll
    for (int j = 0; j < TILE_A / 256; ++j) {
        int p = base + j * 256 + t;
        if (p < P) atomicAdd(&hist[nbr[p].x >> BKT_SHIFT], 1);
    }
    __syncthreads();

    int h0 = hist[2 * t], h1 = hist[2 * t + 1];
    int pairsum = h0 + h1;
    tsum[t] = pairsum;
    __syncthreads();
    for (int o = 1; o < 256; o <<= 1) {
        int v = (t >= o) ? tsum[t - o] : 0;
        __syncthreads();
        tsum[t] += v;
        __syncthreads();
    }
    int ex = tsum[t] - pairsum;
    off[2 * t] = ex;
    off[2 * t + 1] = ex + h0;
    curs[2 * t] = ex;
    curs[2 * t + 1] = ex + h0;
    __syncthreads();

    for (int i = t; i < BKT_MAX; i += 256) {
        int c = hist[i];
        rb[i] = c ? atomicAdd(&bcur[i], c) : 0;
    }
#pragma unroll
    for (int j = 0; j < TILE_A / 256; ++j) {
        int p = base + j * 256 + t;
        if (p < P) {
            int2 e = nbr[p];
            int b = e.x >> BKT_SHIFT;
            int v = (e.y << BKT_SHIFT) | (e.x & ((1 << BKT_SHIFT) - 1));
            int pos = atomicAdd(&curs[b], 1);
            stage_v[pos] = v;
            stage_b[pos] = (unsigned short)b;
        }
    }
    __syncthreads();

    int n = min(TILE_A, P - base);
    for (int idx = t; idx < n; idx += 256) {
        int b = stage_b[idx];
        part[rb[b] + (idx - off[b])] = stage_v[idx];
    }
}

// ---------------- fused aggregate + transform (R6) ----------------

// One block per half-bucket (512 dsts). 512 threads (8 waves), 133 KB LDS:
// fp32 accumulator tile [512][64] + per-wave 64-pair stage. Gather phase:
// waves stream the bucket's part run in interleaved 64-pair chunks; per pair
// all 64 lanes load feat[src][lane] (256B coalesced) and ds_add_f32 into
// acc[dstl&511][lane]. Pairs of the other half are skipped (wave-uniform
// branch). Epilogue: per dst, uniform ds_read_b128 of the acc row + 64 FMA
// against kcol, nt store.
__global__ __launch_bounds__(512) void k_fused(const float* __restrict__ feat,
                                               const int* __restrict__ part,
                                               const int* __restrict__ bbase,
                                               const float* __restrict__ Kmat,
                                               const float* __restrict__ bias,
                                               float* __restrict__ out, int E) {
    __shared__ float accf[NDH * FD];     // 128 KB
    __shared__ int pst_all[8 * 64];      // 2 KB: per-wave pair stage

    const int tid = threadIdx.x;
    const int lane = tid & 63;
    const int wid = tid >> 6;
    const int b = (int)blockIdx.x >> 1;
    const int half = (int)blockIdx.x & 1;

    // zero the accumulator tile
    float4 z = {0.f, 0.f, 0.f, 0.f};
    float4* ap = (float4*)accf;
#pragma unroll
    for (int i = 0; i < (NDH * FD / 4) / 512; ++i) ap[tid + i * 512] = z;

    float kcol[FD];
#pragma unroll
    for (int d = 0; d < FD; ++d) kcol[d] = Kmat[d * FD + lane];
    const float bb = bias[lane];

    __syncthreads();

    const int rb = bbase[b], re = bbase[b + 1];
    int* const pst = pst_all + wid * 64;

    // gather phase: waves take interleaved 64-pair chunks
    for (int c = rb + wid * 64; c < re; c += 512) {
        int idx = c + lane;
        int pv = (idx < re) ? part[idx] : (int)0x80000000;  // sentinel < 0
        pst[lane] = pv;
        // same-wave write->read: compiler orders via lgkmcnt
#pragma unroll
        for (int j = 0; j < 64; j += 8) {
            int4 qa = *(const int4*)(pst + j);       // uniform addr: broadcast
            int4 qb = *(const int4*)(pst + j + 4);
            int pvs[8] = {qa.x, qa.y, qa.z, qa.w, qb.x, qb.y, qb.z, qb.w};
            float f[8];
            bool v[8];
#pragma unroll
            for (int k = 0; k < 8; ++k) {
                int p = pvs[k];
                v[k] = (p >= 0) && (((p >> 9) & 1) == half);
                if (v[k]) f[k] = feat[(size_t)(p >> 10) * FD + lane];
            }
#pragma unroll
            for (int k = 0; k < 8; ++k)
                if (v[k]) atomicAdd(&accf[(pvs[k] & (NDH - 1)) * FD + lane], f[k]);
        }
    }

    __syncthreads();

    // epilogue: transform 512 dsts, 8 waves -> 64 dsts/wave
    const int d0 = (b << BKT_SHIFT) + half * NDH;
    for (int dl = wid; dl < NDH; dl += 8) {
        int d = d0 + dl;
        if (d >= E) break;
        float o = bb;
        const float4* xp = (const float4*)&accf[dl * FD];
#pragma unroll
        for (int j = 0; j < FD / 4; ++j) {
            float4 q = xp[j];
            o += q.x * kcol[4 * j + 0] + q.y * kcol[4 * j + 1] +
                 q.z * kcol[4 * j + 2] + q.w * kcol[4 * j + 3];
        }
        __builtin_nontemporal_store(o, &out[(size_t)d * FD + lane]);
    }
}

// ---------------- old CSR pipeline (fallback #1, unchanged) ----------------

__global__ __launch_bounds__(256) void k_hist(const int* __restrict__ nbr,
                                              int* __restrict__ cnt, int P) {
    int p = blockIdx.x * 256 + threadIdx.x;
    if (p < P) atomicAdd(&cnt[nbr[2 * p]], 1);
}

__global__ __launch_bounds__(256) void k_blocksum(const int* __restrict__ cnt,
                                                  int* __restrict__ bsum, int E) {
    int base = blockIdx.x * 1024;
    int t = threadIdx.x;
    int s = 0;
#pragma unroll
    for (int j = 0; j < 4; ++j) {
        int e = base + t + j * 256;
        if (e < E) s += cnt[e];
    }
    for (int off = 32; off; off >>= 1) s += __shfl_down(s, off, 64);
    __shared__ int wsum[4];
    int wid = t >> 6, lane = t & 63;
    if (lane == 0) wsum[wid] = s;
    __syncthreads();
    if (t == 0) bsum[blockIdx.x] = wsum[0] + wsum[1] + wsum[2] + wsum[3];
}

__global__ __launch_bounds__(1024) void k_scan_bsum(int* bsum, int NB) {
    __shared__ int s[1024];
    int t = threadIdx.x;
    s[t] = (t < NB) ? bsum[t] : 0;
    __syncthreads();
    int orig = s[t];
    for (int off = 1; off < 1024; off <<= 1) {
        int v = (t >= off) ? s[t - off] : 0;
        __syncthreads();
        s[t] += v;
        __syncthreads();
    }
    if (t < NB) bsum[t] = s[t] - orig;
}

__global__ __launch_bounds__(256) void k_scan_write(const int* __restrict__ cnt,
                                                    const int* __restrict__ boff,
                                                    int* __restrict__ offs,
                                                    int* __restrict__ cur,
                                                    int E) {
    __shared__ int tsum[256];
    int b = blockIdx.x, t = threadIdx.x;
    int base = b * 1024 + t * 4;
    int c[4];
#pragma unroll
    for (int j = 0; j < 4; ++j) {
        int e = base + j;
        c[j] = (e < E) ? cnt[e] : 0;
    }
    int local = c[0] + c[1] + c[2] + c[3];
    tsum[t] = local;
    __syncthreads();
    for (int off = 1; off < 256; off <<= 1) {
        int v = (t >= off) ? tsum[t - off] : 0;
        __syncthreads();
        tsum[t] += v;
        __syncthreads();
    }
    int run = tsum[t] - local + boff[b];
#pragma unroll
    for (int j = 0; j < 4; ++j) {
        int e = base + j;
        if (e < E) {
            offs[e] = run;
            cur[e] = run;
            run += c[j];
            if (e == E - 1) offs[E] = run;
        }
    }
}

__global__ __launch_bounds__(256) void k_build(const int* __restrict__ nbr,
                                               int* __restrict__ cur,
                                               int* __restrict__ csr, int P) {
    int p = blockIdx.x * 256 + threadIdx.x;
    if (p < P) {
        int dst = nbr[2 * p + 0];
        int src = nbr[2 * p + 1];
        int pos = atomicAdd(&cur[dst], 1);
        csr[pos] = src;
    }
}

// k_agg (R3 form) kept for the fallback CSR path
__global__ __launch_bounds__(256) void k_agg(const float* __restrict__ feat,
                                             const int* __restrict__ offs,
                                             const int* __restrict__ csr,
                                             const float* __restrict__ Kmat,
                                             const float* __restrict__ bias,
                                             float* __restrict__ out, int E) {
    __shared__ float xr[4][FD];
    const int lane = threadIdx.x & 63;
    const int wid = threadIdx.x >> 6;
    const int g = lane >> 4;
    const int gl = lane & 15;

    float kcol[FD];
#pragma unroll
    for (int d = 0; d < FD; ++d) kcol[d] = Kmat[d * FD + lane];
    const float b = bias[lane];

    const int wv = __builtin_amdgcn_readfirstlane((int)blockIdx.x * 4 + wid);
    const int nw = (int)gridDim.x * 4;
    float4* const xw4 = (float4*)&xr[wid][0];

    for (int e = wv; e < E; e += nw) {
        const int beg = offs[e], end = offs[e + 1];
        float4 a = {0.f, 0.f, 0.f, 0.f};
        int i = beg;
        for (; i + 8 <= end; i += 8) {
            int s0 = csr[i + g], s1 = csr[i + 4 + g];
            const float4 v0 = *(const float4*)&feat[(size_t)s0 * FD + 4 * gl];
            const float4 v1 = *(const float4*)&feat[(size_t)s1 * FD + 4 * gl];
            a.x += v0.x + v1.x;
            a.y += v0.y + v1.y;
            a.z += v0.z + v1.z;
            a.w += v0.w + v1.w;
        }
        for (; i < end; i += 4) {
            int idx = i + g;
            if (idx < end) {
                int s = csr[idx];
                const float4 v = *(const float4*)&feat[(size_t)s * FD + 4 * gl];
                a.x += v.x; a.y += v.y; a.z += v.z; a.w += v.w;
            }
        }
        a.x += __shfl_xor(a.x, 16, 64);
        a.y += __shfl_xor(a.y, 16, 64);
        a.z += __shfl_xor(a.z, 16, 64);
        a.w += __shfl_xor(a.w, 16, 64);
        a.x += __shfl_xor(a.x, 32, 64);
        a.y += __shfl_xor(a.y, 32, 64);
        a.z += __shfl_xor(a.z, 32, 64);
        a.w += __shfl_xor(a.w, 32, 64);

        if (g == 0) xw4[gl] = a;
        float o = b;
        const float4* xp = (const float4*)&xr[wid][0];
#pragma unroll
        for (int j = 0; j < FD / 4; ++j) {
            float4 q = xp[j];
            o += q.x * kcol[4 * j + 0] + q.y * kcol[4 * j + 1] +
                 q.z * kcol[4 * j + 2] + q.w * kcol[4 * j + 3];
        }
        __builtin_nontemporal_store(o, &out[(size_t)e * FD + lane]);
    }
}

// ---------------- fallback #2 (atomic scatter) ----------------

__global__ __launch_bounds__(256) void ea_scatter(const float* __restrict__ feat,
                                                  const int* __restrict__ nbr,
                                                  float* __restrict__ agg, int P) {
    const int lane = threadIdx.x & 63;
    const int pair = __builtin_amdgcn_readfirstlane(
        (int)blockIdx.x * 4 + ((int)threadIdx.x >> 6));
    if (pair < P) {
        const int dst = nbr[2 * pair + 0];
        const int src = nbr[2 * pair + 1];
        atomicAdd(&agg[(size_t)dst * FD + lane], feat[(size_t)src * FD + lane]);
    }
}

__global__ __launch_bounds__(256) void ea_transform(float* __restrict__ io,
                                                    const float* __restrict__ Kmat,
                                                    const float* __restrict__ bias,
                                                    int E) {
    const int lane = threadIdx.x & 63;
    float kcol[FD];
#pragma unroll
    for (int d = 0; d < FD; ++d) kcol[d] = Kmat[d * FD + lane];
    const float b = bias[lane];
    const int wv = __builtin_amdgcn_readfirstlane(
        (int)blockIdx.x * 4 + ((int)threadIdx.x >> 6));
    const int nw = (int)gridDim.x * 4;
    for (int e = wv; e < E; e += nw) {
        const float* __restrict__ row = io + (size_t)e * FD;
        float acc = b;
#pragma unroll
        for (int d = 0; d < FD; ++d) acc += row[d] * kcol[d];
        io[(size_t)e * FD + lane] = acc;
    }
}

// ---------------- launcher ----------------

extern "C" void kernel_launch(void* const* d_in, const int* in_sizes, int n_in,
                              void* d_out, int out_size, void* d_ws, size_t ws_size,
                              hipStream_t stream) {
    const float* feat = (const float*)d_in[0];
    const int* nbr = (const int*)d_in[1];
    const float* Kmat = (const float*)d_in[2];
    const float* bias = (const float*)d_in[3];
    float* out = (float*)d_out;

    const int E = in_sizes[0] / FD;  // 500000
    const int P = in_sizes[1] / 2;   // 4000000
    const int NBKT = (E + (1 << BKT_SHIFT) - 1) >> BKT_SHIFT;
    const int NB = (E + 1023) / 1024;

    const size_t need_new =
        ((size_t)(E + 1) + (BKT_MAX + 1) + BKT_MAX + (size_t)P) * sizeof(int);
    const size_t need_old =
        ((size_t)E + (size_t)(E + 1) + 1024 + (size_t)P) * sizeof(int);

    if (NBKT <= BKT_MAX && ws_size >= need_new) {
        // ---- bucketed build + fused LDS-tile aggregate ----
        int* offs = (int*)d_ws;              // E+1 (unused; layout kept)
        int* bbase = offs + (E + 1);         // BKT_MAX+1
        int* bcur = bbase + (BKT_MAX + 1);   // BKT_MAX (doubles as bcnt)
        int* part = bcur + BKT_MAX;          // P

        hipMemsetAsync(bcur, 0, BKT_MAX * sizeof(int), stream);
        k_bhist<<<(P + 4095) / 4096, 256, 0, stream>>>((const int2*)nbr, bcur, P);
        k_bscan<<<1, BKT_MAX, 0, stream>>>(bcur, bbase, bcur, NBKT, P);
        k_partition<<<(P + TILE_A - 1) / TILE_A, 256, 0, stream>>>(
            (const int2*)nbr, bcur, part, P);
        k_fused<<<2 * NBKT, 512, 0, stream>>>(feat, part, bbase, Kmat, bias, out, E);
    } else if (ws_size >= need_old && NB <= 1024) {
        // ---- old CSR pipeline ----
        int* cur = (int*)d_ws;
        int* offs = cur + E;
        int* bsum = offs + E + 1;
        int* csr = bsum + 1024;

        hipMemsetAsync(cur, 0, (size_t)E * sizeof(int), stream);
        k_hist<<<(P + 255) / 256, 256, 0, stream>>>(nbr, cur, P);
        k_blocksum<<<NB, 256, 0, stream>>>(cur, bsum, E);
        k_scan_bsum<<<1, 1024, 0, stream>>>(bsum, NB);
        k_scan_write<<<NB, 256, 0, stream>>>(cur, bsum, offs, cur, E);
        k_build<<<(P + 255) / 256, 256, 0, stream>>>(nbr, cur, csr, P);
        k_agg<<<4096, 256, 0, stream>>>(feat, offs, csr, Kmat, bias, out, E);
    } else {
        // ---- atomic fallback ----
        hipMemsetAsync(d_out, 0, (size_t)out_size * sizeof(float), stream);
        ea_scatter<<<(P + 3) / 4, 256, 0, stream>>>(feat, nbr, out, P);
        ea_transform<<<2048, 256, 0, stream>>>(out, Kmat, bias, E);
    }
}